// Round 1
// baseline (3988.913 us; speedup 1.0000x reference)
//
#include <hip/hip_runtime.h>
#include <hip/hip_bf16.h>
#include <cstdint>
#include <cstddef>

// Problem dims
#define D_   991     // feature dim
#define DP   992     // padded K (31*32)
#define GP   3072    // padded 3*D -> 3 sections of 1024
#define B_   16384
#define S_   6
#define BC   4096    // batch chunk
#define NCH  4       // number of chunks

typedef __bf16 bf16;
typedef __attribute__((ext_vector_type(8))) __bf16 bf16x8;
typedef __attribute__((ext_vector_type(4))) float f32x4;

// Async global->LDS, 16 B per lane. LDS dest is wave-uniform base + lane*16
// (m104 semantics); our staging layout is exactly linear in tid so this
// reproduces the previous register-staged layout bit-for-bit.
#define GLDS16(gp, lp) __builtin_amdgcn_global_load_lds(               \
    (const __attribute__((address_space(1))) void*)(gp),               \
    (__attribute__((address_space(3))) void*)(lp), 16, 0, 0)

// ---------------------------------------------------------------------------
// GEMM: C[M x GP] = A[M x DP] * W[GP x DP]^T   (both bf16, K-contiguous rows)
// 128x128 tile, BK=32, 256 threads (4 waves, each 64x64 via 4x4 MFMA 16x16x32)
// m97-rung staging: direct async global_load_lds (width=16), 2-barrier loop.
// ---------------------------------------------------------------------------
__global__ __launch_bounds__(256, 2) void gemm_bt(
    const bf16* __restrict__ A, const bf16* __restrict__ W,
    float* __restrict__ C)
{
  __shared__ __align__(16) bf16 As[128 * 32];
  __shared__ __align__(16) bf16 Bs[128 * 32];

  const int tid  = threadIdx.x;
  const int lane = tid & 63;
  const int wave = tid >> 6;
  const int bm = blockIdx.y;
  const int bn = blockIdx.x;

  // Staging: lane l of wave w covers LDS bytes (w*64+l)*16, i.e.
  // row = w*16 + (l>>2)  (row stride 32 bf16 = 64 B), col = (l&3)*8 bf16.
  const int srow = tid >> 2;               // 0..63
  const int scol = (tid & 3) << 3;         // {0,8,16,24} bf16 elems
  const bf16* aP = A + (size_t)(bm * 128 + srow) * DP + scol;
  const bf16* bP = W + (size_t)(bn * 128 + srow) * DP + scol;
  bf16* asW = &As[wave * 512];             // wave-uniform dest (1024 B apart)
  bf16* bsW = &Bs[wave * 512];

  const int wr = (wave >> 1) << 6;   // 0 or 64 (M quadrant)
  const int wc = (wave & 1) << 6;    // 0 or 64 (N quadrant)
  const int frow = lane & 15;
  const int fq   = lane >> 4;

  f32x4 acc[4][4];
#pragma unroll
  for (int i = 0; i < 4; i++)
#pragma unroll
    for (int j = 0; j < 4; j++) acc[i][j] = (f32x4){0.f, 0.f, 0.f, 0.f};

  for (int k0 = 0; k0 < DP; k0 += 32) {
    __syncthreads();   // all waves done reading LDS from previous iteration
    GLDS16(aP + k0,                     asW);          // A rows  0..63
    GLDS16(aP + (size_t)64 * DP + k0,   asW + 2048);   // A rows 64..127
    GLDS16(bP + k0,                     bsW);          // W rows  0..63
    GLDS16(bP + (size_t)64 * DP + k0,   bsW + 2048);   // W rows 64..127
    __syncthreads();   // compiler drains vmcnt(0) before s_barrier

    bf16x8 af[4], bfr[4];
#pragma unroll
    for (int mt = 0; mt < 4; mt++)
      af[mt] = *(const bf16x8*)&As[(wr + mt * 16 + frow) * 32 + fq * 8];
#pragma unroll
    for (int nt = 0; nt < 4; nt++)
      bfr[nt] = *(const bf16x8*)&Bs[(wc + nt * 16 + frow) * 32 + fq * 8];
#pragma unroll
    for (int mt = 0; mt < 4; mt++)
#pragma unroll
      for (int nt = 0; nt < 4; nt++)
        acc[mt][nt] = __builtin_amdgcn_mfma_f32_16x16x32_bf16(
            af[mt], bfr[nt], acc[mt][nt], 0, 0, 0);
  }

  // epilogue: C/D layout col=lane&15, row=(lane>>4)*4+i
  const int rbase = bm * 128 + wr + fq * 4;
  const int cbase = bn * 128 + wc + frow;
#pragma unroll
  for (int mt = 0; mt < 4; mt++)
#pragma unroll
    for (int nt = 0; nt < 4; nt++) {
      float* cp = C + (size_t)(rbase + mt * 16) * GP + cbase + nt * 16;
#pragma unroll
      for (int i = 0; i < 4; i++) cp[(size_t)i * GP] = acc[mt][nt][i];
    }
}

// ---------------------------------------------------------------------------
// Pad/relayout W_ih, W_hh (2973x991 fp32) -> (3072x992) bf16 with
// 1024-aligned sections and zero padding.
// ---------------------------------------------------------------------------
__global__ __launch_bounds__(256) void pad_w(
    const float* __restrict__ Wih, const float* __restrict__ Whh,
    bf16* __restrict__ Wihp, bf16* __restrict__ Whhp)
{
  int idx = blockIdx.x * 256 + threadIdx.x;
  if (idx >= GP * DP) return;
  int c = idx % DP;
  int p = idx / DP;
  int sec = p >> 10;
  int j = p & 1023;
  bf16 vi = (bf16)0.0f, vh = (bf16)0.0f;
  if (j < D_ && c < D_) {
    size_t src = ((size_t)sec * D_ + j) * D_ + c;
    vi = (bf16)Wih[src];
    vh = (bf16)Whh[src];
  }
  Wihp[idx] = vi;
  Whhp[idx] = vh;
}

// ---------------------------------------------------------------------------
// Fold final linears: Wc[o][d] = sum_j W2[o][j]*W1[j][d];  bc[o]=W2@b1+b2
// ---------------------------------------------------------------------------
__global__ __launch_bounds__(256) void wc_fold(
    const float* __restrict__ W1, const float* __restrict__ b1,
    const float* __restrict__ W2, const float* __restrict__ b2,
    float* __restrict__ wc)
{
  int idx = blockIdx.x * 256 + threadIdx.x;
  if (idx < 2 * D_) {
    int o = idx / D_;
    int d = idx - o * D_;
    float acc = 0.f;
    for (int j = 0; j < 2 * D_; j++)
      acc += W2[o * 2 * D_ + j] * W1[(size_t)j * D_ + d];
    wc[idx] = acc;
  } else if (idx < 2 * D_ + 2) {
    int o = idx - 2 * D_;
    float acc = b2[o];
    for (int j = 0; j < 2 * D_; j++)
      acc += W2[o * 2 * D_ + j] * b1[j];
    wc[2 * D_ + o] = acc;
  }
}

// ---------------------------------------------------------------------------
// Embedding gather + LayerNorm for one (chunk, step) -> xcur (BC, DP) bf16
// ---------------------------------------------------------------------------
__global__ __launch_bounds__(256) void embed_ln(
    const int* __restrict__ node_seq, const int* __restrict__ fin_seq,
    const int* __restrict__ nfin_seq, const int* __restrict__ mda_seq,
    const float* __restrict__ node_t, const float* __restrict__ fin_t,
    const float* __restrict__ nfin_t, const float* __restrict__ bert_t,
    const float* __restrict__ ln_g, const float* __restrict__ ln_b,
    bf16* __restrict__ xout, int base, int t)
{
  const int bl = blockIdx.x;                 // 0..BC-1
  const int bid = (base + bl) * S_ + t;      // index into (B,S) seqs
  const int tid = threadIdx.x;
  const int ni = node_seq[bid];
  const int fi = fin_seq[bid];
  const int nf = nfin_seq[bid];
  const int mi = mda_seq[bid];

  float v[4];
  float s1 = 0.f, s2 = 0.f;
#pragma unroll
  for (int k = 0; k < 4; k++) {
    int d = tid + (k << 8);
    float val = 0.f;
    if (d < D_) {
      if (d < 128)       val = node_t[(size_t)ni * 128 + d];
      else if (d < 212)  val = fin_t[(size_t)fi * 84 + (d - 128)];
      else if (d < 223)  val = nfin_t[(size_t)nf * 11 + (d - 212)];
      else               val = bert_t[(size_t)mi * 768 + (d - 223)];
    }
    v[k] = val;
    s1 += val;
    s2 += val * val;
  }
#pragma unroll
  for (int off = 32; off > 0; off >>= 1) {
    s1 += __shfl_down(s1, off);
    s2 += __shfl_down(s2, off);
  }
  __shared__ float red[8];
  const int wave = tid >> 6, lane = tid & 63;
  if (lane == 0) { red[wave] = s1; red[4 + wave] = s2; }
  __syncthreads();
  s1 = red[0] + red[1] + red[2] + red[3];
  s2 = red[4] + red[5] + red[6] + red[7];
  const float mean = s1 * (1.0f / D_);
  const float rstd = rsqrtf(s2 * (1.0f / D_) - mean * mean + 1e-5f);

  bf16* row = xout + (size_t)bl * DP;
#pragma unroll
  for (int k = 0; k < 4; k++) {
    int d = tid + (k << 8);
    if (d < D_)
      row[d] = (bf16)(((v[k] - mean) * rstd) * ln_g[d] + ln_b[d]);
    else if (d == D_)
      row[d] = (bf16)0.0f;
  }
}

// ---------------------------------------------------------------------------
// GRU gates for one chunk: h' = (1-z)*n + z*h ; writes h fp32, hb bf16, and
// the selected output row (global index) when t == seq_len-1.
// ---------------------------------------------------------------------------
__global__ __launch_bounds__(256) void gru_gate(
    const float* __restrict__ Gx, const float* __restrict__ Gh,
    const float* __restrict__ b_ih, const float* __restrict__ b_hh,
    float* __restrict__ h, bf16* __restrict__ hb, float* __restrict__ outb,
    const int* __restrict__ seq_len, int base, int t, int first)
{
  const int bl = blockIdx.x;                // local row
  const int bg = base + bl;                 // global batch row
  const int tid = threadIdx.x;
  const int sel = (seq_len[bg] - 1 == t);
  const float* gx = Gx + (size_t)bl * GP;
  const float* gh = Gh + (size_t)bl * GP;
  const size_t hrow = (size_t)bl * DP;
  const size_t orow = (size_t)bg * DP;

#pragma unroll
  for (int k = 0; k < 4; k++) {
    int d = tid + (k << 8);
    if (d < D_) {
      float xr = gx[d]        + b_ih[d];
      float xz = gx[1024 + d] + b_ih[D_ + d];
      float xn = gx[2048 + d] + b_ih[2 * D_ + d];
      float hr = b_hh[d];
      float hz = b_hh[D_ + d];
      float hn = b_hh[2 * D_ + d];
      float hp = 0.f;
      if (!first) {
        hr += gh[d];
        hz += gh[1024 + d];
        hn += gh[2048 + d];
        hp = h[hrow + d];
      }
      float r = 1.f / (1.f + expf(-(xr + hr)));
      float z = 1.f / (1.f + expf(-(xz + hz)));
      float n = tanhf(xn + r * hn);
      float hv = (1.f - z) * n + z * hp;
      h[hrow + d] = hv;
      hb[hrow + d] = (bf16)hv;
      if (sel) outb[orow + d] = hv;
    } else if (d == D_) {
      h[hrow + d] = 0.f;
      hb[hrow + d] = (bf16)0.0f;
      if (sel) outb[orow + d] = 0.f;
    }
  }
}

// ---------------------------------------------------------------------------
// BatchNorm stats: per-column sum / sumsq over B rows (partial + atomics)
// ---------------------------------------------------------------------------
__global__ __launch_bounds__(256) void bn_stats(
    const float* __restrict__ outb, float* __restrict__ sums,
    float* __restrict__ sumsq)
{
  const int tid = threadIdx.x;
  const int b0 = blockIdx.x << 8;
  float a[4] = {0.f, 0.f, 0.f, 0.f}, q[4] = {0.f, 0.f, 0.f, 0.f};
  for (int r = 0; r < 256; r++) {
    const float* row = outb + (size_t)(b0 + r) * DP;
#pragma unroll
    for (int k = 0; k < 4; k++) {
      int d = tid + (k << 8);
      if (d < D_) {
        float v = row[d];
        a[k] += v;
        q[k] += v * v;
      }
    }
  }
#pragma unroll
  for (int k = 0; k < 4; k++) {
    int d = tid + (k << 8);
    if (d < D_) {
      atomicAdd(&sums[d], a[k]);
      atomicAdd(&sumsq[d], q[k]);
    }
  }
}

// ---------------------------------------------------------------------------
// Final: BN normalize + folded (W2@W1) linear -> logits fp32. 1 wave / row.
// ---------------------------------------------------------------------------
__global__ __launch_bounds__(256) void final_k(
    const float* __restrict__ outb, const float* __restrict__ sums,
    const float* __restrict__ sumsq, const float* __restrict__ bn_g,
    const float* __restrict__ bn_b, const float* __restrict__ wc,
    float* __restrict__ out)
{
  const int wave = threadIdx.x >> 6, lane = threadIdx.x & 63;
  const int b = (blockIdx.x << 2) + wave;
  const float* row = outb + (size_t)b * DP;
  float p0 = 0.f, p1 = 0.f;
  for (int d = lane; d < D_; d += 64) {
    float mean = sums[d] * (1.0f / B_);
    float var  = sumsq[d] * (1.0f / B_) - mean * mean;
    float sc = bn_g[d] * rsqrtf(var + 1e-4f);
    float v = (row[d] - mean) * sc + bn_b[d];
    p0 += v * wc[d];
    p1 += v * wc[D_ + d];
  }
#pragma unroll
  for (int off = 32; off > 0; off >>= 1) {
    p0 += __shfl_down(p0, off);
    p1 += __shfl_down(p1, off);
  }
  if (lane == 0) {
    out[(size_t)b * 2]     = p0 + wc[2 * D_];
    out[(size_t)b * 2 + 1] = p1 + wc[2 * D_ + 1];
  }
}

// ---------------------------------------------------------------------------
// Workspace layout (bytes) — total ~210.4 MB
// ---------------------------------------------------------------------------
static const size_t OFF_WIHP = 0;                                  // 6,094,848
static const size_t OFF_WHHP = OFF_WIHP + (size_t)GP * DP * 2;
static const size_t OFF_XCUR = OFF_WHHP + (size_t)GP * DP * 2;     // 8,126,464
static const size_t OFF_GX   = OFF_XCUR + (size_t)BC * DP * 2;     // 50,331,648
static const size_t OFF_GH   = OFF_GX + (size_t)BC * GP * 4;
static const size_t OFF_H    = OFF_GH + (size_t)BC * GP * 4;       // 16,252,928
static const size_t OFF_HB   = OFF_H + (size_t)BC * DP * 4;        //  8,126,464
static const size_t OFF_OUTB = OFF_HB + (size_t)BC * DP * 2;       // 65,011,712
static const size_t OFF_BN   = OFF_OUTB + (size_t)B_ * DP * 4;     //      8,192
static const size_t OFF_WC   = OFF_BN + 8192;                      //      8,192
static const size_t REQUIRED = OFF_WC + 8192;                      // 210,386,944

extern "C" void kernel_launch(void* const* d_in, const int* in_sizes, int n_in,
                              void* d_out, int out_size, void* d_ws, size_t ws_size,
                              hipStream_t stream)
{
  // Diagnostic guard: too-small workspace -> zero-ish output (finite absmax
  // ~1.4375 signals "ws too small"; NaN would mean a logic bug instead).
  if (ws_size < REQUIRED) {
    hipMemsetAsync(d_out, 0, (size_t)out_size * 2, stream);
    return;
  }

  const int*   node_seq = (const int*)d_in[0];
  const int*   fin_seq  = (const int*)d_in[1];
  const int*   nfin_seq = (const int*)d_in[2];
  const int*   mda_seq  = (const int*)d_in[3];
  const int*   seq_len  = (const int*)d_in[4];
  const float* node_t   = (const float*)d_in[5];
  const float* fin_t    = (const float*)d_in[6];
  const float* nfin_t   = (const float*)d_in[7];
  const float* bert_t   = (const float*)d_in[8];
  const float* ln_g     = (const float*)d_in[9];
  const float* ln_b     = (const float*)d_in[10];
  const float* W_ih     = (const float*)d_in[11];
  const float* W_hh     = (const float*)d_in[12];
  const float* b_ih     = (const float*)d_in[13];
  const float* b_hh     = (const float*)d_in[14];
  const float* bn_gv    = (const float*)d_in[15];
  const float* bn_bv    = (const float*)d_in[16];
  const float* W1       = (const float*)d_in[17];
  const float* b1       = (const float*)d_in[18];
  const float* W2       = (const float*)d_in[19];
  const float* b2       = (const float*)d_in[20];

  char* ws = (char*)d_ws;
  bf16*  Wihp  = (bf16*)(ws + OFF_WIHP);
  bf16*  Whhp  = (bf16*)(ws + OFF_WHHP);
  bf16*  xcur  = (bf16*)(ws + OFF_XCUR);
  float* Gx    = (float*)(ws + OFF_GX);
  float* Gh    = (float*)(ws + OFF_GH);
  float* h     = (float*)(ws + OFF_H);
  bf16*  hb    = (bf16*)(ws + OFF_HB);
  float* outb  = (float*)(ws + OFF_OUTB);
  float* bnsum = (float*)(ws + OFF_BN);       // [1024] sums, [1024] sumsq
  float* wcbuf = (float*)(ws + OFF_WC);

  pad_w<<<(GP * DP + 255) / 256, 256, 0, stream>>>(W_ih, W_hh, Wihp, Whhp);
  wc_fold<<<8, 256, 0, stream>>>(W1, b1, W2, b2, wcbuf);
  hipMemsetAsync(bnsum, 0, 8192, stream);

  dim3 ggrid(GP / 128, BC / 128);
  for (int ch = 0; ch < NCH; ch++) {
    const int base = ch * BC;
    for (int t = 0; t < S_; t++) {
      embed_ln<<<BC, 256, 0, stream>>>(node_seq, fin_seq, nfin_seq, mda_seq,
                                       node_t, fin_t, nfin_t, bert_t,
                                       ln_g, ln_b, xcur, base, t);
      gemm_bt<<<ggrid, 256, 0, stream>>>(xcur, Wihp, Gx);
      if (t > 0)
        gemm_bt<<<ggrid, 256, 0, stream>>>(hb, Whhp, Gh);
      gru_gate<<<BC, 256, 0, stream>>>(Gx, Gh, b_ih, b_hh, h, hb, outb,
                                       seq_len, base, t, t == 0 ? 1 : 0);
    }
  }

  bn_stats<<<64, 256, 0, stream>>>(outb, bnsum, bnsum + 1024);
  final_k<<<B_ / 4, 256, 0, stream>>>(outb, bnsum, bnsum + 1024,
                                      bn_gv, bn_bv, wcbuf, (float*)d_out);
}

// Round 2
// 3031.317 us; speedup vs baseline: 1.3159x; 1.3159x over previous
//
#include <hip/hip_runtime.h>
#include <hip/hip_bf16.h>
#include <cstdint>
#include <cstddef>

// Problem dims
#define D_   991     // feature dim
#define DP   992     // padded K (31*32)
#define GP   3072    // padded 3*D -> 3 sections of 1024
#define B_   16384
#define S_   6

typedef __bf16 bf16;
typedef __attribute__((ext_vector_type(8))) __bf16 bf16x8;
typedef __attribute__((ext_vector_type(4))) float f32x4;

// Async global->LDS, 16 B per lane. LDS dest is wave-uniform base + lane*16
// (m104 semantics); staging layout is exactly linear in tid.
#define GLDS16(gp, lp) __builtin_amdgcn_global_load_lds(               \
    (const __attribute__((address_space(1))) void*)(gp),               \
    (__attribute__((address_space(3))) void*)(lp), 16, 0, 0)

// ---------------------------------------------------------------------------
// Paired GEMM: for z = 0 (and 1 when grid.z==2):
//   Cz[M x GP] = Az[M x DP] * Wz[GP x DP]^T   (bf16 in, fp32 out)
// 128x128 tile, BK=32, 256 threads (4 waves, each 64x64 via 4x4 MFMA 16x16x32)
// Direct async global_load_lds (width=16), 2-barrier loop (m97 rung).
// Merging the two per-step GEMMs into one dispatch kills the 1.5-wave tail
// (768 blocks on 512 slots -> 1536 = 3 exact waves).
// ---------------------------------------------------------------------------
__global__ __launch_bounds__(256, 2) void gemm_bt2(
    const bf16* __restrict__ A0, const bf16* __restrict__ W0,
    float* __restrict__ C0,
    const bf16* __restrict__ A1, const bf16* __restrict__ W1,
    float* __restrict__ C1)
{
  __shared__ __align__(16) bf16 As[128 * 32];
  __shared__ __align__(16) bf16 Bs[128 * 32];

  const bf16* A = blockIdx.z ? A1 : A0;
  const bf16* W = blockIdx.z ? W1 : W0;
  float*      C = blockIdx.z ? C1 : C0;

  const int tid  = threadIdx.x;
  const int lane = tid & 63;
  const int wave = tid >> 6;
  const int bm = blockIdx.y;
  const int bn = blockIdx.x;

  // Staging: lane l of wave w covers LDS bytes (w*64+l)*16 (linear in tid).
  const int srow = tid >> 2;               // 0..63
  const int scol = (tid & 3) << 3;         // {0,8,16,24} bf16 elems
  const bf16* aP = A + (size_t)(bm * 128 + srow) * DP + scol;
  const bf16* bP = W + (size_t)(bn * 128 + srow) * DP + scol;
  bf16* asW = &As[wave * 512];             // wave-uniform dest (1024 B apart)
  bf16* bsW = &Bs[wave * 512];

  const int wr = (wave >> 1) << 6;   // 0 or 64 (M quadrant)
  const int wc = (wave & 1) << 6;    // 0 or 64 (N quadrant)
  const int frow = lane & 15;
  const int fq   = lane >> 4;

  f32x4 acc[4][4];
#pragma unroll
  for (int i = 0; i < 4; i++)
#pragma unroll
    for (int j = 0; j < 4; j++) acc[i][j] = (f32x4){0.f, 0.f, 0.f, 0.f};

  for (int k0 = 0; k0 < DP; k0 += 32) {
    __syncthreads();   // all waves done reading LDS from previous iteration
    GLDS16(aP + k0,                     asW);          // A rows  0..63
    GLDS16(aP + (size_t)64 * DP + k0,   asW + 2048);   // A rows 64..127
    GLDS16(bP + k0,                     bsW);          // W rows  0..63
    GLDS16(bP + (size_t)64 * DP + k0,   bsW + 2048);   // W rows 64..127
    __syncthreads();   // compiler drains vmcnt(0) before s_barrier

    bf16x8 af[4], bfr[4];
#pragma unroll
    for (int mt = 0; mt < 4; mt++)
      af[mt] = *(const bf16x8*)&As[(wr + mt * 16 + frow) * 32 + fq * 8];
#pragma unroll
    for (int nt = 0; nt < 4; nt++)
      bfr[nt] = *(const bf16x8*)&Bs[(wc + nt * 16 + frow) * 32 + fq * 8];
#pragma unroll
    for (int mt = 0; mt < 4; mt++)
#pragma unroll
      for (int nt = 0; nt < 4; nt++)
        acc[mt][nt] = __builtin_amdgcn_mfma_f32_16x16x32_bf16(
            af[mt], bfr[nt], acc[mt][nt], 0, 0, 0);
  }

  // epilogue: C/D layout col=lane&15, row=(lane>>4)*4+i
  const int rbase = bm * 128 + wr + fq * 4;
  const int cbase = bn * 128 + wc + frow;
#pragma unroll
  for (int mt = 0; mt < 4; mt++)
#pragma unroll
    for (int nt = 0; nt < 4; nt++) {
      float* cp = C + (size_t)(rbase + mt * 16) * GP + cbase + nt * 16;
#pragma unroll
      for (int i = 0; i < 4; i++) cp[(size_t)i * GP] = acc[mt][nt][i];
    }
}

// ---------------------------------------------------------------------------
// Pad/relayout W_ih, W_hh (2973x991 fp32) -> (3072x992) bf16 with
// 1024-aligned sections and zero padding.
// ---------------------------------------------------------------------------
__global__ __launch_bounds__(256) void pad_w(
    const float* __restrict__ Wih, const float* __restrict__ Whh,
    bf16* __restrict__ Wihp, bf16* __restrict__ Whhp)
{
  int idx = blockIdx.x * 256 + threadIdx.x;
  if (idx >= GP * DP) return;
  int c = idx % DP;
  int p = idx / DP;
  int sec = p >> 10;
  int j = p & 1023;
  bf16 vi = (bf16)0.0f, vh = (bf16)0.0f;
  if (j < D_ && c < D_) {
    size_t src = ((size_t)sec * D_ + j) * D_ + c;
    vi = (bf16)Wih[src];
    vh = (bf16)Whh[src];
  }
  Wihp[idx] = vi;
  Whhp[idx] = vh;
}

// ---------------------------------------------------------------------------
// Fold final linears: wc[o*D+d] = sum_j W2[o][j]*W1[j][d];  wc[2D+o]=W2@b1+b2
// Parallel version: grid (124 j-chunks x 2 outputs), coalesced W1 row reads,
// atomicAdd into pre-zeroed wc. Replaces the 680 us serial version (~6 us).
// ---------------------------------------------------------------------------
#define WCJ 16
__global__ __launch_bounds__(256) void wc_fold(
    const float* __restrict__ W1, const float* __restrict__ b1,
    const float* __restrict__ W2, const float* __restrict__ b2,
    float* __restrict__ wc)
{
  const int o   = blockIdx.y;               // 0..1
  const int j0  = blockIdx.x * WCJ;
  const int tid = threadIdx.x;
  const int jend = min(j0 + WCJ, 2 * D_);

  float acc[4] = {0.f, 0.f, 0.f, 0.f};
  for (int j = j0; j < jend; j++) {
    float w2 = W2[o * 2 * D_ + j];          // wave-uniform -> scalar load
#pragma unroll
    for (int k = 0; k < 4; k++) {
      int d = tid + (k << 8);
      if (d < D_) acc[k] += w2 * W1[(size_t)j * D_ + d];
    }
  }
#pragma unroll
  for (int k = 0; k < 4; k++) {
    int d = tid + (k << 8);
    if (d < D_) atomicAdd(&wc[o * D_ + d], acc[k]);
  }
  // bias partial over this j-chunk (lanes 0..15 of wave 0)
  float pb = 0.f;
  if (tid < WCJ && (j0 + tid) < 2 * D_)
    pb = W2[o * 2 * D_ + j0 + tid] * b1[j0 + tid];
  for (int off = 8; off > 0; off >>= 1) pb += __shfl_down(pb, off);
  if (tid == 0) {
    float add = pb + (blockIdx.x == 0 ? b2[o] : 0.f);
    atomicAdd(&wc[2 * D_ + o], add);
  }
}

// ---------------------------------------------------------------------------
// Embedding gather + LayerNorm for one (chunk, step) -> xcur (bc, DP) bf16
// ---------------------------------------------------------------------------
__global__ __launch_bounds__(256) void embed_ln(
    const int* __restrict__ node_seq, const int* __restrict__ fin_seq,
    const int* __restrict__ nfin_seq, const int* __restrict__ mda_seq,
    const float* __restrict__ node_t, const float* __restrict__ fin_t,
    const float* __restrict__ nfin_t, const float* __restrict__ bert_t,
    const float* __restrict__ ln_g, const float* __restrict__ ln_b,
    bf16* __restrict__ xout, int base, int t)
{
  const int bl = blockIdx.x;                 // local row
  const int bid = (base + bl) * S_ + t;      // index into (B,S) seqs
  const int tid = threadIdx.x;
  const int ni = node_seq[bid];
  const int fi = fin_seq[bid];
  const int nf = nfin_seq[bid];
  const int mi = mda_seq[bid];

  float v[4];
  float s1 = 0.f, s2 = 0.f;
#pragma unroll
  for (int k = 0; k < 4; k++) {
    int d = tid + (k << 8);
    float val = 0.f;
    if (d < D_) {
      if (d < 128)       val = node_t[(size_t)ni * 128 + d];
      else if (d < 212)  val = fin_t[(size_t)fi * 84 + (d - 128)];
      else if (d < 223)  val = nfin_t[(size_t)nf * 11 + (d - 212)];
      else               val = bert_t[(size_t)mi * 768 + (d - 223)];
    }
    v[k] = val;
    s1 += val;
    s2 += val * val;
  }
#pragma unroll
  for (int off = 32; off > 0; off >>= 1) {
    s1 += __shfl_down(s1, off);
    s2 += __shfl_down(s2, off);
  }
  __shared__ float red[8];
  const int wave = tid >> 6, lane = tid & 63;
  if (lane == 0) { red[wave] = s1; red[4 + wave] = s2; }
  __syncthreads();
  s1 = red[0] + red[1] + red[2] + red[3];
  s2 = red[4] + red[5] + red[6] + red[7];
  const float mean = s1 * (1.0f / D_);
  const float rstd = rsqrtf(s2 * (1.0f / D_) - mean * mean + 1e-5f);

  bf16* row = xout + (size_t)bl * DP;
#pragma unroll
  for (int k = 0; k < 4; k++) {
    int d = tid + (k << 8);
    if (d < D_)
      row[d] = (bf16)(((v[k] - mean) * rstd) * ln_g[d] + ln_b[d]);
    else if (d == D_)
      row[d] = (bf16)0.0f;
  }
}

// ---------------------------------------------------------------------------
// GRU gates for one chunk: h' = (1-z)*n + z*h ; writes h fp32, hb bf16, and
// the selected output row (global index) when t == seq_len-1.
// ---------------------------------------------------------------------------
__global__ __launch_bounds__(256) void gru_gate(
    const float* __restrict__ Gx, const float* __restrict__ Gh,
    const float* __restrict__ b_ih, const float* __restrict__ b_hh,
    float* __restrict__ h, bf16* __restrict__ hb, float* __restrict__ outb,
    const int* __restrict__ seq_len, int base, int t, int first)
{
  const int bl = blockIdx.x;                // local row
  const int bg = base + bl;                 // global batch row
  const int tid = threadIdx.x;
  const int sel = (seq_len[bg] - 1 == t);
  const float* gx = Gx + (size_t)bl * GP;
  const float* gh = Gh + (size_t)bl * GP;
  const size_t hrow = (size_t)bl * DP;
  const size_t orow = (size_t)bg * DP;

#pragma unroll
  for (int k = 0; k < 4; k++) {
    int d = tid + (k << 8);
    if (d < D_) {
      float xr = gx[d]        + b_ih[d];
      float xz = gx[1024 + d] + b_ih[D_ + d];
      float xn = gx[2048 + d] + b_ih[2 * D_ + d];
      float hr = b_hh[d];
      float hz = b_hh[D_ + d];
      float hn = b_hh[2 * D_ + d];
      float hp = 0.f;
      if (!first) {
        hr += gh[d];
        hz += gh[1024 + d];
        hn += gh[2048 + d];
        hp = h[hrow + d];
      }
      float r = 1.f / (1.f + expf(-(xr + hr)));
      float z = 1.f / (1.f + expf(-(xz + hz)));
      float n = tanhf(xn + r * hn);
      float hv = (1.f - z) * n + z * hp;
      h[hrow + d] = hv;
      hb[hrow + d] = (bf16)hv;
      if (sel) outb[orow + d] = hv;
    } else if (d == D_) {
      h[hrow + d] = 0.f;
      hb[hrow + d] = (bf16)0.0f;
      if (sel) outb[orow + d] = 0.f;
    }
  }
}

// ---------------------------------------------------------------------------
// BatchNorm stats: per-column sum / sumsq over B rows (partial + atomics)
// 256 blocks x 64 rows each.
// ---------------------------------------------------------------------------
__global__ __launch_bounds__(256) void bn_stats(
    const float* __restrict__ outb, float* __restrict__ sums,
    float* __restrict__ sumsq)
{
  const int tid = threadIdx.x;
  const int b0 = blockIdx.x << 6;
  float a[4] = {0.f, 0.f, 0.f, 0.f}, q[4] = {0.f, 0.f, 0.f, 0.f};
  for (int r = 0; r < 64; r++) {
    const float* row = outb + (size_t)(b0 + r) * DP;
#pragma unroll
    for (int k = 0; k < 4; k++) {
      int d = tid + (k << 8);
      if (d < D_) {
        float v = row[d];
        a[k] += v;
        q[k] += v * v;
      }
    }
  }
#pragma unroll
  for (int k = 0; k < 4; k++) {
    int d = tid + (k << 8);
    if (d < D_) {
      atomicAdd(&sums[d], a[k]);
      atomicAdd(&sumsq[d], q[k]);
    }
  }
}

// ---------------------------------------------------------------------------
// Final: BN normalize + folded (W2@W1) linear -> logits fp32. 1 wave / row.
// ---------------------------------------------------------------------------
__global__ __launch_bounds__(256) void final_k(
    const float* __restrict__ outb, const float* __restrict__ sums,
    const float* __restrict__ sumsq, const float* __restrict__ bn_g,
    const float* __restrict__ bn_b, const float* __restrict__ wc,
    float* __restrict__ out)
{
  const int wave = threadIdx.x >> 6, lane = threadIdx.x & 63;
  const int b = (blockIdx.x << 2) + wave;
  const float* row = outb + (size_t)b * DP;
  float p0 = 0.f, p1 = 0.f;
  for (int d = lane; d < D_; d += 64) {
    float mean = sums[d] * (1.0f / B_);
    float var  = sumsq[d] * (1.0f / B_) - mean * mean;
    float sc = bn_g[d] * rsqrtf(var + 1e-4f);
    float v = (row[d] - mean) * sc + bn_b[d];
    p0 += v * wc[d];
    p1 += v * wc[D_ + d];
  }
#pragma unroll
  for (int off = 32; off > 0; off >>= 1) {
    p0 += __shfl_down(p0, off);
    p1 += __shfl_down(p1, off);
  }
  if (lane == 0) {
    out[(size_t)b * 2]     = p0 + wc[2 * D_];
    out[(size_t)b * 2 + 1] = p1 + wc[2 * D_ + 1];
  }
}

// ---------------------------------------------------------------------------
// Workspace: runtime-adaptive chunk size bc in {16384, 8192, 4096}.
// REQ(bc) = weights(12,189,696) + outb(65,011,712) + bn/wc(16,384)
//         + bc * (xcur 2 + Gx 4*GP/DP... ) = 77,217,792 + bc*32512 bytes.
// bc=4096 reproduces the previous verified 210,386,944-byte layout exactly.
// ---------------------------------------------------------------------------
static inline size_t ws_required(size_t bc) {
  return 77217792ull + bc * 32512ull;
}

extern "C" void kernel_launch(void* const* d_in, const int* in_sizes, int n_in,
                              void* d_out, int out_size, void* d_ws, size_t ws_size,
                              hipStream_t stream)
{
  // Pick the largest chunk size that fits the provided workspace.
  int bc;
  if      (ws_size >= ws_required(16384)) bc = 16384;
  else if (ws_size >= ws_required(8192))  bc = 8192;
  else if (ws_size >= ws_required(4096))  bc = 4096;
  else {
    // Diagnostic guard: too-small workspace -> zero output (finite small
    // absmax signals "ws too small"; NaN would mean a logic bug instead).
    hipMemsetAsync(d_out, 0, (size_t)out_size * 2, stream);
    return;
  }
  const int nch = B_ / bc;

  const int*   node_seq = (const int*)d_in[0];
  const int*   fin_seq  = (const int*)d_in[1];
  const int*   nfin_seq = (const int*)d_in[2];
  const int*   mda_seq  = (const int*)d_in[3];
  const int*   seq_len  = (const int*)d_in[4];
  const float* node_t   = (const float*)d_in[5];
  const float* fin_t    = (const float*)d_in[6];
  const float* nfin_t   = (const float*)d_in[7];
  const float* bert_t   = (const float*)d_in[8];
  const float* ln_g     = (const float*)d_in[9];
  const float* ln_b     = (const float*)d_in[10];
  const float* W_ih     = (const float*)d_in[11];
  const float* W_hh     = (const float*)d_in[12];
  const float* b_ih     = (const float*)d_in[13];
  const float* b_hh     = (const float*)d_in[14];
  const float* bn_gv    = (const float*)d_in[15];
  const float* bn_bv    = (const float*)d_in[16];
  const float* W1       = (const float*)d_in[17];
  const float* b1       = (const float*)d_in[18];
  const float* W2       = (const float*)d_in[19];
  const float* b2       = (const float*)d_in[20];

  char* ws = (char*)d_ws;
  size_t off = 0;
  bf16*  Wihp  = (bf16*)(ws + off);  off += (size_t)GP * DP * 2;
  bf16*  Whhp  = (bf16*)(ws + off);  off += (size_t)GP * DP * 2;
  bf16*  xcur  = (bf16*)(ws + off);  off += (size_t)bc * DP * 2;
  float* Gx    = (float*)(ws + off); off += (size_t)bc * GP * 4;
  float* Gh    = (float*)(ws + off); off += (size_t)bc * GP * 4;
  float* h     = (float*)(ws + off); off += (size_t)bc * DP * 4;
  bf16*  hb    = (bf16*)(ws + off);  off += (size_t)bc * DP * 2;
  float* outb  = (float*)(ws + off); off += (size_t)B_ * DP * 4;
  float* bnsum = (float*)(ws + off); off += 8192;   // [1024] sums, [1024] sumsq
  float* wcbuf = (float*)(ws + off); off += 8192;

  pad_w<<<(GP * DP + 255) / 256, 256, 0, stream>>>(W_ih, W_hh, Wihp, Whhp);
  hipMemsetAsync(bnsum, 0, 16384, stream);   // zeros bnsum AND wcbuf (adjacent)
  dim3 wcg((2 * D_ + WCJ - 1) / WCJ, 2);
  wc_fold<<<wcg, 256, 0, stream>>>(W1, b1, W2, b2, wcbuf);

  for (int ch = 0; ch < nch; ch++) {
    const int base = ch * bc;
    for (int t = 0; t < S_; t++) {
      embed_ln<<<bc, 256, 0, stream>>>(node_seq, fin_seq, nfin_seq, mda_seq,
                                       node_t, fin_t, nfin_t, bert_t,
                                       ln_g, ln_b, xcur, base, t);
      dim3 g2(GP / 128, bc / 128, t > 0 ? 2 : 1);
      gemm_bt2<<<g2, 256, 0, stream>>>(xcur, Wihp, Gx, hb, Whhp, Gh);
      gru_gate<<<bc, 256, 0, stream>>>(Gx, Gh, b_ih, b_hh, h, hb, outb,
                                       seq_len, base, t, t == 0 ? 1 : 0);
    }
  }

  bn_stats<<<256, 256, 0, stream>>>(outb, bnsum, bnsum + 1024);
  final_k<<<B_ / 4, 256, 0, stream>>>(outb, bnsum, bnsum + 1024,
                                      bn_gv, bn_bv, wcbuf, (float*)d_out);
}

// Round 3
// 2911.068 us; speedup vs baseline: 1.3703x; 1.0413x over previous
//
#include <hip/hip_runtime.h>
#include <hip/hip_bf16.h>
#include <cstdint>
#include <cstddef>

// Problem dims
#define D_   991     // feature dim
#define B_   16384
#define S_   6
#define KP   2048    // concat K: [x(991) pad->1024 | h(991) pad->1024]
#define GPN  4096    // G cols: [rz-combined 2048 | n_x 1024 | n_h 1024]
#define WROWS 4096   // W_cat rows: r, z, n_x, n_h sections of 1024

typedef __bf16 bf16;
typedef __attribute__((ext_vector_type(8))) __bf16 bf16x8;
typedef __attribute__((ext_vector_type(4))) float f32x4;

// Async global->LDS, 16 B per lane (m104 semantics: dest = wave base + lane*16).
#define GLDS16(gp, lp) __builtin_amdgcn_global_load_lds(               \
    (const __attribute__((address_space(1))) void*)(gp),               \
    (__attribute__((address_space(3))) void*)(lp), 16, 0, 0)

// ---------------------------------------------------------------------------
// Concat GEMM: G[M x GPN] = A_cat[M x KP] * W_cat[WROWS x KP]^T, bf16->fp32.
// Column section determines K-range:
//   bn  0..15 (rz): k in [0,2048)   (first step: [0,1024) since h==0)
//   bn 16..23 (n_x): k in [0,1024)
//   bn 24..31 (n_h): k in [1024,2048)  (skipped entirely when first)
// 128x128 tile, BK=32, 4 waves, 4x4 MFMA 16x16x32, global_load_lds staging.
// ---------------------------------------------------------------------------
__global__ __launch_bounds__(256, 2) void gemm_cat(
    const bf16* __restrict__ A, const bf16* __restrict__ W,
    float* __restrict__ C, int first)
{
  __shared__ __align__(16) bf16 As[128 * 32];
  __shared__ __align__(16) bf16 Bs[128 * 32];

  const int tid  = threadIdx.x;
  const int lane = tid & 63;
  const int wave = tid >> 6;
  const int bn = blockIdx.x;
  const int bm = blockIdx.y;

  int ks, ke;
  if (bn < 16)      { ks = 0;    ke = first ? 1024 : 2048; }
  else if (bn < 24) { ks = 0;    ke = 1024; }
  else              { ks = 1024; ke = 2048; }

  // Staging: lane l of wave w covers LDS bytes (w*64+l)*16 (linear in tid).
  const int srow = tid >> 2;               // 0..63
  const int scol = (tid & 3) << 3;         // {0,8,16,24} bf16 elems
  const bf16* aP = A + (size_t)(bm * 128 + srow) * KP + scol;
  const bf16* bP = W + (size_t)(bn * 128 + srow) * KP + scol;
  bf16* asW = &As[wave * 512];             // wave-uniform dest
  bf16* bsW = &Bs[wave * 512];

  const int wr = (wave >> 1) << 6;   // 0 or 64 (M quadrant)
  const int wc = (wave & 1) << 6;    // 0 or 64 (N quadrant)
  const int frow = lane & 15;
  const int fq   = lane >> 4;

  f32x4 acc[4][4];
#pragma unroll
  for (int i = 0; i < 4; i++)
#pragma unroll
    for (int j = 0; j < 4; j++) acc[i][j] = (f32x4){0.f, 0.f, 0.f, 0.f};

  for (int k0 = ks; k0 < ke; k0 += 32) {
    __syncthreads();   // all waves done reading LDS from previous iteration
    GLDS16(aP + k0,                    asW);          // A rows  0..63
    GLDS16(aP + (size_t)64 * KP + k0,  asW + 2048);   // A rows 64..127
    GLDS16(bP + k0,                    bsW);          // W rows  0..63
    GLDS16(bP + (size_t)64 * KP + k0,  bsW + 2048);   // W rows 64..127
    __syncthreads();   // compiler drains vmcnt(0) before s_barrier

    bf16x8 af[4], bfr[4];
#pragma unroll
    for (int mt = 0; mt < 4; mt++)
      af[mt] = *(const bf16x8*)&As[(wr + mt * 16 + frow) * 32 + fq * 8];
#pragma unroll
    for (int nt = 0; nt < 4; nt++)
      bfr[nt] = *(const bf16x8*)&Bs[(wc + nt * 16 + frow) * 32 + fq * 8];
#pragma unroll
    for (int mt = 0; mt < 4; mt++)
#pragma unroll
      for (int nt = 0; nt < 4; nt++)
        acc[mt][nt] = __builtin_amdgcn_mfma_f32_16x16x32_bf16(
            af[mt], bfr[nt], acc[mt][nt], 0, 0, 0);
  }

  // epilogue: C/D layout col=lane&15, row=(lane>>4)*4+i
  const int rbase = bm * 128 + wr + fq * 4;
  const int cbase = bn * 128 + wc + frow;
#pragma unroll
  for (int mt = 0; mt < 4; mt++)
#pragma unroll
    for (int nt = 0; nt < 4; nt++) {
      float* cp = C + (size_t)(rbase + mt * 16) * GPN + cbase + nt * 16;
#pragma unroll
      for (int i = 0; i < 4; i++) cp[(size_t)i * GPN] = acc[mt][nt][i];
    }
}

// ---------------------------------------------------------------------------
// Build W_cat[4096][2048] bf16:
//   rows    0..1023 (r):   [W_ih_r | W_hh_r]
//   rows 1024..2047 (z):   [W_ih_z | W_hh_z]
//   rows 2048..3071 (n_x): [W_ih_n | 0     ]
//   rows 3072..4095 (n_h): [0      | W_hh_n]
// W_ih/W_hh are (2973 x 991) fp32, gate g rows at g*991+j.
// ---------------------------------------------------------------------------
__global__ __launch_bounds__(256) void pad_wcat(
    const float* __restrict__ Wih, const float* __restrict__ Whh,
    bf16* __restrict__ Wc)
{
  int idx = blockIdx.x * 256 + threadIdx.x;   // over 4096*2048
  int c = idx & (KP - 1);
  int r = idx >> 11;
  int sec = r >> 10;
  int j = r & 1023;
  float v = 0.f;
  if (j < D_) {
    if (c < D_) {                 // x-half, col c
      int g = (sec == 0) ? 0 : (sec == 1) ? 1 : (sec == 2) ? 2 : -1;
      if (g >= 0) v = Wih[((size_t)g * D_ + j) * D_ + c];
    } else if (c >= 1024 && c < 1024 + D_) {   // h-half, col c-1024
      int g = (sec == 0) ? 0 : (sec == 1) ? 1 : (sec == 3) ? 2 : -1;
      if (g >= 0) v = Whh[((size_t)g * D_ + j) * D_ + (c - 1024)];
    }
  }
  Wc[idx] = (bf16)v;
}

// ---------------------------------------------------------------------------
// Fold final linears: wc[o*D+d] = sum_j W2[o][j]*W1[j][d];  wc[2D+o]=W2@b1+b2
// Parallel: grid (j-chunks x 2), coalesced W1 rows, atomicAdd into zeroed wc.
// ---------------------------------------------------------------------------
#define WCJ 16
__global__ __launch_bounds__(256) void wc_fold(
    const float* __restrict__ W1, const float* __restrict__ b1,
    const float* __restrict__ W2, const float* __restrict__ b2,
    float* __restrict__ wc)
{
  const int o   = blockIdx.y;               // 0..1
  const int j0  = blockIdx.x * WCJ;
  const int tid = threadIdx.x;
  const int jend = min(j0 + WCJ, 2 * D_);

  float acc[4] = {0.f, 0.f, 0.f, 0.f};
  for (int j = j0; j < jend; j++) {
    float w2 = W2[o * 2 * D_ + j];
#pragma unroll
    for (int k = 0; k < 4; k++) {
      int d = tid + (k << 8);
      if (d < D_) acc[k] += w2 * W1[(size_t)j * D_ + d];
    }
  }
#pragma unroll
  for (int k = 0; k < 4; k++) {
    int d = tid + (k << 8);
    if (d < D_) atomicAdd(&wc[o * D_ + d], acc[k]);
  }
  float pb = 0.f;
  if (tid < WCJ && (j0 + tid) < 2 * D_)
    pb = W2[o * 2 * D_ + j0 + tid] * b1[j0 + tid];
  for (int off = 8; off > 0; off >>= 1) pb += __shfl_down(pb, off);
  if (tid == 0) {
    float add = pb + (blockIdx.x == 0 ? b2[o] : 0.f);
    atomicAdd(&wc[2 * D_ + o], add);
  }
}

// ---------------------------------------------------------------------------
// Embedding gather + LayerNorm -> x-half of A_cat (row stride KP), pads zeroed.
// ---------------------------------------------------------------------------
__global__ __launch_bounds__(256) void embed_ln(
    const int* __restrict__ node_seq, const int* __restrict__ fin_seq,
    const int* __restrict__ nfin_seq, const int* __restrict__ mda_seq,
    const float* __restrict__ node_t, const float* __restrict__ fin_t,
    const float* __restrict__ nfin_t, const float* __restrict__ bert_t,
    const float* __restrict__ ln_g, const float* __restrict__ ln_b,
    bf16* __restrict__ acat, int base, int t)
{
  const int bl = blockIdx.x;                 // local row
  const int bid = (base + bl) * S_ + t;      // index into (B,S) seqs
  const int tid = threadIdx.x;
  const int ni = node_seq[bid];
  const int fi = fin_seq[bid];
  const int nf = nfin_seq[bid];
  const int mi = mda_seq[bid];

  float v[4];
  float s1 = 0.f, s2 = 0.f;
#pragma unroll
  for (int k = 0; k < 4; k++) {
    int d = tid + (k << 8);
    float val = 0.f;
    if (d < D_) {
      if (d < 128)       val = node_t[(size_t)ni * 128 + d];
      else if (d < 212)  val = fin_t[(size_t)fi * 84 + (d - 128)];
      else if (d < 223)  val = nfin_t[(size_t)nf * 11 + (d - 212)];
      else               val = bert_t[(size_t)mi * 768 + (d - 223)];
    }
    v[k] = val;
    s1 += val;
    s2 += val * val;
  }
#pragma unroll
  for (int off = 32; off > 0; off >>= 1) {
    s1 += __shfl_down(s1, off);
    s2 += __shfl_down(s2, off);
  }
  __shared__ float red[8];
  const int wave = tid >> 6, lane = tid & 63;
  if (lane == 0) { red[wave] = s1; red[4 + wave] = s2; }
  __syncthreads();
  s1 = red[0] + red[1] + red[2] + red[3];
  s2 = red[4] + red[5] + red[6] + red[7];
  const float mean = s1 * (1.0f / D_);
  const float rstd = rsqrtf(s2 * (1.0f / D_) - mean * mean + 1e-5f);

  bf16* row = acat + (size_t)bl * KP;
#pragma unroll
  for (int k = 0; k < 4; k++) {
    int d = tid + (k << 8);                  // covers 0..1023 (x half + pad)
    if (d < D_)
      row[d] = (bf16)(((v[k] - mean) * rstd) * ln_g[d] + ln_b[d]);
    else
      row[d] = (bf16)0.0f;
  }
}

// ---------------------------------------------------------------------------
// GRU gates from concat G:
//   r = sig(G[d]      + b_ih_r + b_hh_r)          (G rz has x+h combined)
//   z = sig(G[1024+d] + b_ih_z + b_hh_z)
//   n = tanh((G[2048+d]+b_ih_n) + r*(G[3072+d]+b_hh_n))
//   h' = (1-z)*n + z*h
// Writes h fp32, h-bf16 into A_cat h-half (pads zeroed), selected row to outb.
// ---------------------------------------------------------------------------
__global__ __launch_bounds__(256) void gru_gate(
    const float* __restrict__ G, const float* __restrict__ b_ih,
    const float* __restrict__ b_hh, float* __restrict__ h,
    bf16* __restrict__ acat, float* __restrict__ outb,
    const int* __restrict__ seq_len, int base, int t, int first)
{
  const int bl = blockIdx.x;                // local row
  const int bg = base + bl;                 // global batch row
  const int tid = threadIdx.x;
  const int sel = (seq_len[bg] - 1 == t);
  const float* g = G + (size_t)bl * GPN;
  float* hrow = h + (size_t)bl * 1024;
  bf16*  hbr  = acat + (size_t)bl * KP + 1024;   // h-half of A_cat
  float* orow = outb + (size_t)bg * 1024;

#pragma unroll
  for (int k = 0; k < 4; k++) {
    int d = tid + (k << 8);                 // 0..1023
    if (d < D_) {
      float rpre = g[d]        + b_ih[d]          + b_hh[d];
      float zpre = g[1024 + d] + b_ih[D_ + d]     + b_hh[D_ + d];
      float nx   = g[2048 + d] + b_ih[2 * D_ + d];
      float nh   = (first ? 0.f : g[3072 + d]) + b_hh[2 * D_ + d];
      float hp   = first ? 0.f : hrow[d];
      float r = 1.f / (1.f + expf(-rpre));
      float z = 1.f / (1.f + expf(-zpre));
      float n = tanhf(nx + r * nh);
      float hv = (1.f - z) * n + z * hp;
      hrow[d] = hv;
      hbr[d]  = (bf16)hv;
      if (sel) orow[d] = hv;
    } else {                                // pads 991..1023
      hbr[d] = (bf16)0.0f;
      if (sel) orow[d] = 0.f;
    }
  }
}

// ---------------------------------------------------------------------------
// BatchNorm stats: per-column sum / sumsq over B rows (partial + atomics)
// ---------------------------------------------------------------------------
__global__ __launch_bounds__(256) void bn_stats(
    const float* __restrict__ outb, float* __restrict__ sums,
    float* __restrict__ sumsq)
{
  const int tid = threadIdx.x;
  const int b0 = blockIdx.x << 6;
  float a[4] = {0.f, 0.f, 0.f, 0.f}, q[4] = {0.f, 0.f, 0.f, 0.f};
  for (int r = 0; r < 64; r++) {
    const float* row = outb + (size_t)(b0 + r) * 1024;
#pragma unroll
    for (int k = 0; k < 4; k++) {
      int d = tid + (k << 8);
      if (d < D_) {
        float v = row[d];
        a[k] += v;
        q[k] += v * v;
      }
    }
  }
#pragma unroll
  for (int k = 0; k < 4; k++) {
    int d = tid + (k << 8);
    if (d < D_) {
      atomicAdd(&sums[d], a[k]);
      atomicAdd(&sumsq[d], q[k]);
    }
  }
}

// ---------------------------------------------------------------------------
// Final: BN normalize + folded (W2@W1) linear -> logits fp32. 1 wave / row.
// ---------------------------------------------------------------------------
__global__ __launch_bounds__(256) void final_k(
    const float* __restrict__ outb, const float* __restrict__ sums,
    const float* __restrict__ sumsq, const float* __restrict__ bn_g,
    const float* __restrict__ bn_b, const float* __restrict__ wc,
    float* __restrict__ out)
{
  const int wave = threadIdx.x >> 6, lane = threadIdx.x & 63;
  const int b = (blockIdx.x << 2) + wave;
  const float* row = outb + (size_t)b * 1024;
  float p0 = 0.f, p1 = 0.f;
  for (int d = lane; d < D_; d += 64) {
    float mean = sums[d] * (1.0f / B_);
    float var  = sumsq[d] * (1.0f / B_) - mean * mean;
    float sc = bn_g[d] * rsqrtf(var + 1e-4f);
    float v = (row[d] - mean) * sc + bn_b[d];
    p0 += v * wc[d];
    p1 += v * wc[D_ + d];
  }
#pragma unroll
  for (int off = 32; off > 0; off >>= 1) {
    p0 += __shfl_down(p0, off);
    p1 += __shfl_down(p1, off);
  }
  if (lane == 0) {
    out[(size_t)b * 2]     = p0 + wc[2 * D_];
    out[(size_t)b * 2 + 1] = p1 + wc[2 * D_ + 1];
  }
}

// ---------------------------------------------------------------------------
// Workspace: adaptive chunk bc in {16384, 8192, 4096}.
// fixed = W_cat 16,777,216 + outb 67,108,864 + 16,384 = 83,902,464
// per-bc = A_cat 4096 + G 16384 + h 4096 = 24,576 B
// ---------------------------------------------------------------------------
static inline size_t ws_required(size_t bc) {
  return 83902464ull + bc * 24576ull;
}

extern "C" void kernel_launch(void* const* d_in, const int* in_sizes, int n_in,
                              void* d_out, int out_size, void* d_ws, size_t ws_size,
                              hipStream_t stream)
{
  int bc;
  if      (ws_size >= ws_required(16384)) bc = 16384;
  else if (ws_size >= ws_required(8192))  bc = 8192;
  else if (ws_size >= ws_required(4096))  bc = 4096;
  else {
    hipMemsetAsync(d_out, 0, (size_t)out_size * 2, stream);
    return;
  }
  const int nch = B_ / bc;

  const int*   node_seq = (const int*)d_in[0];
  const int*   fin_seq  = (const int*)d_in[1];
  const int*   nfin_seq = (const int*)d_in[2];
  const int*   mda_seq  = (const int*)d_in[3];
  const int*   seq_len  = (const int*)d_in[4];
  const float* node_t   = (const float*)d_in[5];
  const float* fin_t    = (const float*)d_in[6];
  const float* nfin_t   = (const float*)d_in[7];
  const float* bert_t   = (const float*)d_in[8];
  const float* ln_g     = (const float*)d_in[9];
  const float* ln_b     = (const float*)d_in[10];
  const float* W_ih     = (const float*)d_in[11];
  const float* W_hh     = (const float*)d_in[12];
  const float* b_ih     = (const float*)d_in[13];
  const float* b_hh     = (const float*)d_in[14];
  const float* bn_gv    = (const float*)d_in[15];
  const float* bn_bv    = (const float*)d_in[16];
  const float* W1       = (const float*)d_in[17];
  const float* b1       = (const float*)d_in[18];
  const float* W2       = (const float*)d_in[19];
  const float* b2       = (const float*)d_in[20];

  char* ws = (char*)d_ws;
  size_t off = 0;
  bf16*  Wcat  = (bf16*)(ws + off);  off += (size_t)WROWS * KP * 2;
  bf16*  Acat  = (bf16*)(ws + off);  off += (size_t)bc * KP * 2;
  float* G     = (float*)(ws + off); off += (size_t)bc * GPN * 4;
  float* h     = (float*)(ws + off); off += (size_t)bc * 1024 * 4;
  float* outb  = (float*)(ws + off); off += (size_t)B_ * 1024 * 4;
  float* bnsum = (float*)(ws + off); off += 8192;   // [1024] sums, [1024] sumsq
  float* wcbuf = (float*)(ws + off); off += 8192;

  pad_wcat<<<(WROWS * KP) / 256, 256, 0, stream>>>(W_ih, W_hh, Wcat);
  hipMemsetAsync(bnsum, 0, 16384, stream);   // zeros bnsum AND wcbuf (adjacent)
  dim3 wcg((2 * D_ + WCJ - 1) / WCJ, 2);
  wc_fold<<<wcg, 256, 0, stream>>>(W1, b1, W2, b2, wcbuf);

  for (int ch = 0; ch < nch; ch++) {
    const int base = ch * bc;
    for (int t = 0; t < S_; t++) {
      const int first = (t == 0) ? 1 : 0;
      embed_ln<<<bc, 256, 0, stream>>>(node_seq, fin_seq, nfin_seq, mda_seq,
                                       node_t, fin_t, nfin_t, bert_t,
                                       ln_g, ln_b, Acat, base, t);
      dim3 gg(first ? 24 : 32, bc / 128);   // first step: skip n_h section
      gemm_cat<<<gg, 256, 0, stream>>>(Acat, Wcat, G, first);
      gru_gate<<<bc, 256, 0, stream>>>(G, b_ih, b_hh, h, Acat, outb,
                                       seq_len, base, t, first);
    }
  }

  bn_stats<<<256, 256, 0, stream>>>(outb, bnsum, bnsum + 1024);
  final_k<<<B_ / 4, 256, 0, stream>>>(outb, bnsum, bnsum + 1024,
                                      bn_gv, bn_bv, wcbuf, (float*)d_out);
}